// Round 3
// baseline (100.913 us; speedup 1.0000x reference)
//
#include <hip/hip_runtime.h>
#include <math.h>

// Problem constants
#define BB   64
#define LL   4096
#define DKC  128
#define DVC  128
#define HC   4
#define DKLC 64
#define DVLC 128
#define RC   128
#define NSPLIT 64
#define CHUNK  (LL / NSPLIT)   // 64 rows per split

// ---------------------------------------------------------------------------
// Kernel 0: fold q[h][d] = sum_k Wq[h,k] * Wk[d,h,k]   (H*DK = 512 values)
// ---------------------------------------------------------------------------
__global__ __launch_bounds__(512) void k_foldq(const float* __restrict__ Wq,
                                               const float* __restrict__ Wk,
                                               float* __restrict__ q) {
    int t = threadIdx.x;            // 0..511
    int h = t >> 7;                 // 0..3
    int d = t & 127;                // 0..127
    float acc = 0.f;
#pragma unroll 8
    for (int k = 0; k < DKLC; ++k)
        acc += Wq[h * DKLC + k] * Wk[(d * HC + h) * DKLC + k];
    q[h * DKC + d] = acc;
}

// ---------------------------------------------------------------------------
// Fused kernel, one block per (b, 64-row chunk):
//  - all global loads issued up front (K->regs->LDS, V->regs, mask, q->LDS)
//  - stage 1: one (row,head) per thread, dot from padded LDS (no shuffles)
//  - stage 2: in-register softmax stats (wave w == head w, lane == row)
//  - stage 3: WVp from V registers + P broadcast, shfl+LDS tree reduce
// ---------------------------------------------------------------------------
__global__ __launch_bounds__(256) void k_fused(const float* __restrict__ K,
                                               const float* __restrict__ V,
                                               const int*   __restrict__ mask,
                                               const float* __restrict__ q,
                                               float* __restrict__ stats,
                                               float* __restrict__ part) {
    const int bid = blockIdx.x;
    const int b   = bid >> 6;              // NSPLIT = 64
    const int sp  = bid & (NSPLIT - 1);
    const int l0  = sp * CHUNK;
    const int t   = threadIdx.x;
    const int rg  = t >> 5;                // 0..7 row group (stage 3)
    const int i4  = t & 31;                // float4 column
    const int r1  = t & 63;                // row   (stage 1/2)
    const int h1  = t >> 6;                // head  (stage 1/2) == wave id

    __shared__ float4 Ks[CHUNK * 33];      // rows padded to 33 float4 (33.8 KB)
    __shared__ float4 qs4[HC * 32];        // 2 KB
    __shared__ float  P[HC][CHUNK];        // 1 KB
    __shared__ float  wred[HC][2];

    const float4* Kg = (const float4*)(K + ((long)b * LL + l0) * DKC);
    const float4* Vg = (const float4*)(V + ((long)b * LL + l0) * DVC);

    // ---- issue ALL global loads up front ----
    float4 kreg[8], vreg[8];
#pragma unroll
    for (int j = 0; j < 8; ++j) kreg[j] = Kg[j * 256 + t];      // coalesced
#pragma unroll
    for (int it = 0; it < 8; ++it) vreg[it] = Vg[it * 256 + t]; // == (it*8+rg)*32+i4
    int mk = mask[(long)b * LL + l0 + r1];
    if (t < 128) qs4[t] = ((const float4*)q)[t];

    // scatter K into padded LDS rows (row r at float4 slot r*33)
#pragma unroll
    for (int j = 0; j < 8; ++j) {
        int g = j * 256 + t;
        Ks[(g >> 5) * 33 + (g & 31)] = kreg[j];
    }
    __syncthreads();

    // ---- stage 1: score for (row r1, head h1), no cross-lane ops ----
    float a = 0.f;
#pragma unroll
    for (int c = 0; c < 32; ++c) {
        float4 kv = Ks[r1 * 33 + c];       // 8-way spread (b128 floor)
        float4 qv = qs4[h1 * 32 + c];      // wave-uniform -> broadcast
        a += kv.x * qv.x + kv.y * qv.y + kv.z * qv.z + kv.w * qv.w;
    }
    const float scale = 0.08838834764831844f;   // 1/sqrt(128)
    float sval = mk ? -INFINITY : a * scale;

    // ---- stage 2: softmax stats fully in-register (wave = head) ----
    float m = sval;
#pragma unroll
    for (int off = 32; off; off >>= 1) m = fmaxf(m, __shfl_xor(m, off));
    float mu = (m == -INFINITY) ? 0.f : m;     // all-masked chunk guard
    float p  = expf(sval - mu);
    float z  = p;
#pragma unroll
    for (int off = 32; off; off >>= 1) z += __shfl_xor(z, off);
    P[h1][r1] = p;
    if (r1 == 0) { wred[h1][0] = m; wred[h1][1] = z; }
    __syncthreads();

    if (t < HC) {
        stats[(long)bid * 8 + t]     = wred[t][0];   // chunk max (may be -inf)
        stats[(long)bid * 8 + 4 + t] = wred[t][1];   // Z partial
    }

    // ---- stage 3: WVp accumulation from V registers ----
    float4 acc[HC];
#pragma unroll
    for (int h = 0; h < HC; ++h) acc[h] = make_float4(0.f, 0.f, 0.f, 0.f);
#pragma unroll
    for (int it = 0; it < 8; ++it) {
        float4 vv = vreg[it];
#pragma unroll
        for (int h = 0; h < HC; ++h) {
            float wt = P[h][it * 8 + rg];  // 2 addrs per wave -> broadcast
            acc[h].x += wt * vv.x; acc[h].y += wt * vv.y;
            acc[h].z += wt * vv.z; acc[h].w += wt * vv.w;
        }
    }
    // combine row-group pairs: rg and rg^1 sit in the same wave (lane ^ 32)
#pragma unroll
    for (int h = 0; h < HC; ++h) {
        acc[h].x += __shfl_xor(acc[h].x, 32);
        acc[h].y += __shfl_xor(acc[h].y, 32);
        acc[h].z += __shfl_xor(acc[h].z, 32);
        acc[h].w += __shfl_xor(acc[h].w, 32);
    }
    // 4 remaining row groups (one per wave) -> LDS (aliased over dead Ks)
    float4* red2 = Ks;                     // needs 4*4*32 = 512 float4 (8 KB)
    if ((t & 63) < 32) {
#pragma unroll
        for (int h = 0; h < HC; ++h)
            red2[(h1 * HC + h) * 32 + i4] = acc[h];
    }
    __syncthreads();
    if (t < 128) {
        int h = t >> 5, c = t & 31;
        float4 s0 = red2[(0 * HC + h) * 32 + c];
        float4 s1 = red2[(1 * HC + h) * 32 + c];
        float4 s2 = red2[(2 * HC + h) * 32 + c];
        float4 s3 = red2[(3 * HC + h) * 32 + c];
        float4 o;
        o.x = s0.x + s1.x + s2.x + s3.x;
        o.y = s0.y + s1.y + s2.y + s3.y;
        o.z = s0.z + s1.z + s2.z + s3.z;
        o.w = s0.w + s1.w + s2.w + s3.w;
        ((float4*)part)[((long)bid * HC + h) * 32 + c] = o;
    }
}

// ---------------------------------------------------------------------------
// Epilogue: combine split partials (softmax rescale), then
// QKV = (1/L) * WV*Wv ; out = QKV*Wo      one block per b
// ---------------------------------------------------------------------------
__global__ __launch_bounds__(256) void k_out(const float* __restrict__ stats,
                                             const float* __restrict__ part,
                                             const float* __restrict__ Wv,
                                             const float* __restrict__ Wo,
                                             float* __restrict__ out) {
    int b = blockIdx.x;
    int t = threadIdx.x;
    __shared__ float WV[HC][DVC];        // 2 KB
    __shared__ float QKV[HC * DVLC];     // 2 KB
    __shared__ float sc[NSPLIT][HC];     // rescale factors (1 KB)
    __shared__ float zs[HC];

    if (t < HC) {
        float m = -INFINITY;
        for (int p = 0; p < NSPLIT; ++p)
            m = fmaxf(m, stats[((long)b * NSPLIT + p) * 8 + t]);
        float Z = 0.f;
        for (int p = 0; p < NSPLIT; ++p) {
            float s = expf(stats[((long)b * NSPLIT + p) * 8 + t] - m);
            sc[p][t] = s;
            Z += s * stats[((long)b * NSPLIT + p) * 8 + 4 + t];
        }
        zs[t] = Z;
    }
    __syncthreads();

    for (int j = t; j < HC * DVC; j += 256) {
        int h = j >> 7, e = j & 127;
        float a = 0.f;
#pragma unroll 8
        for (int p = 0; p < NSPLIT; ++p)
            a += sc[p][h] * part[(((long)b * NSPLIT + p) * HC + h) * DVC + e];
        WV[h][e] = a / zs[h];
    }
    __syncthreads();

    for (int j = t; j < HC * DVLC; j += 256) {
        int h = j >> 7, vv = j & 127;
        float a = 0.f;
#pragma unroll 8
        for (int e = 0; e < DVC; ++e)
            a += WV[h][e] * Wv[(e * HC + h) * DVLC + vv];
        QKV[j] = a * (1.0f / LL);
    }
    __syncthreads();

    for (int r = t; r < RC; r += 256) {
        float a = 0.f;
#pragma unroll 8
        for (int i = 0; i < HC * DVLC; ++i)
            a += QKV[i] * Wo[i * RC + r];
        out[b * RC + r] = a;
    }
}

// ---------------------------------------------------------------------------
extern "C" void kernel_launch(void* const* d_in, const int* in_sizes, int n_in,
                              void* d_out, int out_size, void* d_ws, size_t ws_size,
                              hipStream_t stream) {
    (void)in_sizes; (void)n_in; (void)out_size; (void)ws_size;
    const float* K    = (const float*)d_in[0];
    const float* V    = (const float*)d_in[1];
    const int*   mask = (const int*)  d_in[2];
    const float* Wq   = (const float*)d_in[3];
    const float* Wk   = (const float*)d_in[4];
    const float* Wv   = (const float*)d_in[5];
    const float* Wo   = (const float*)d_in[6];
    float* out = (float*)d_out;

    float* q     = (float*)d_ws;                          // 512 floats
    float* stats = q + 512;                               // B*NSPLIT*8 = 32768
    float* part  = stats + (long)BB * NSPLIT * 8;         // B*NSPLIT*H*DV = 2M floats

    k_foldq<<<1, 512, 0, stream>>>(Wq, Wk, q);
    k_fused<<<BB * NSPLIT, 256, 0, stream>>>(K, V, mask, q, stats, part);
    k_out<<<BB, 256, 0, stream>>>(stats, part, Wv, Wo, out);
}